// Round 6
// baseline (1589.622 us; speedup 1.0000x reference)
//
#include <hip/hip_runtime.h>
#include <stdint.h>

#define BB 16
#define NN 4096
#define DD 128
#define MM 1024
#define RADIUS2 0.04f
#define TPB 64             // ONE wave per graph: no barriers, no cross-wave sync
#define PPT 64             // points per lane: 64*64 = 4096
#define NPAIR (PPT / 2)    // 32 f32x2 pairs

typedef unsigned long long u64;
typedef unsigned int u32;
typedef float f32x2 __attribute__((ext_vector_type(2)));
typedef unsigned int uint2v __attribute__((ext_vector_type(2)));

__device__ __forceinline__ u32 umin2(u32 a, u32 b) { return a < b ? a : b; }
__device__ __forceinline__ u32 umin3(u32 a, u32 b, u32 c) { return umin2(umin2(a, b), c); }

template <int CTRL>
__device__ __forceinline__ float dpp_fmax(float v) {
    int o = __builtin_amdgcn_update_dpp(0, __float_as_int(v), CTRL, 0xF, 0xF, true);
    return fmaxf(v, __int_as_float(o));
}
template <int CTRL>
__device__ __forceinline__ u32 dpp_umin(u32 v) {
    u32 o = (u32)__builtin_amdgcn_update_dpp(0, (int)v, CTRL, 0xF, 0xF, true);
    return umin2(v, o);
}
__device__ __forceinline__ float xor16_fmax(float v) {
#if __has_builtin(__builtin_amdgcn_permlane16_swap)
    uint2v r = __builtin_amdgcn_permlane16_swap(__float_as_uint(v), __float_as_uint(v), false, false);
    return fmaxf(__uint_as_float(r[0]), __uint_as_float(r[1]));
#else
    int o = __builtin_amdgcn_ds_swizzle(__float_as_int(v), 0x401F);
    return fmaxf(v, __int_as_float(o));
#endif
}
__device__ __forceinline__ u32 xor16_umin(u32 v) {
#if __has_builtin(__builtin_amdgcn_permlane16_swap)
    uint2v r = __builtin_amdgcn_permlane16_swap(v, v, false, false);
    return umin2(r[0], r[1]);
#else
    u32 o = (u32)__builtin_amdgcn_ds_swizzle((int)v, 0x401F);
    return umin2(v, o);
#endif
}
__device__ __forceinline__ float xor32_fmax(float v) {
#if __has_builtin(__builtin_amdgcn_permlane32_swap)
    uint2v r = __builtin_amdgcn_permlane32_swap(__float_as_uint(v), __float_as_uint(v), false, false);
    return fmaxf(__uint_as_float(r[0]), __uint_as_float(r[1]));
#else
    return fmaxf(v, __shfl_xor(v, 32, 64));
#endif
}
__device__ __forceinline__ u32 xor32_umin(u32 v) {
#if __has_builtin(__builtin_amdgcn_permlane32_swap)
    uint2v r = __builtin_amdgcn_permlane32_swap(v, v, false, false);
    return umin2(r[0], r[1]);
#else
    return umin2(v, __shfl_xor(v, 32, 64));
#endif
}
__device__ __forceinline__ float wave_fmax(float v) {
    v = dpp_fmax<0xB1>(v);     // quad_perm xor1
    v = dpp_fmax<0x4E>(v);     // quad_perm xor2
    v = dpp_fmax<0x141>(v);    // row_half_mirror
    v = dpp_fmax<0x140>(v);    // row_mirror
    v = xor16_fmax(v);
    v = xor32_fmax(v);
    return v;
}
__device__ __forceinline__ u32 wave_umin(u32 v) {
    v = dpp_umin<0xB1>(v);
    v = dpp_umin<0x4E>(v);
    v = dpp_umin<0x141>(v);
    v = dpp_umin<0x140>(v);
    v = xor16_umin(v);
    v = xor32_umin(v);
    return v;
}

// ---------------------------------------------------------------------------
// FPS: ONE wave per graph. 64 points/lane in registers. Per iteration:
//   pk dist update -> ILP max tree -> local equality scan (4 accumulators)
//   -> wave_fmax -> select -> wave_umin -> owner-lane readlane broadcast.
// Zero barriers, zero LDS partials: removes the ~1200cy/iter cross-wave
// sync stall that r3-r5 edits never moved. Tie-break = lowest index at
// every level (scan umin within lane; ascending lane ranges + umin across).
// ---------------------------------------------------------------------------
__global__ __launch_bounds__(TPB) void fps_kernel(const float* __restrict__ pos,
                                                  int* __restrict__ idx_out) {
    const int b    = blockIdx.x;
    const int lane = threadIdx.x;

    __shared__ float4 pos4[NN];        // xyz_ padded; speculative winner reads

    const float* pg = pos + (size_t)b * NN * 3;
    for (int k = lane; k < NN * 3; k += TPB)
        ((float*)&pos4[k / 3])[k % 3] = pg[k];
    __syncthreads();                   // single wave: trivial, just LDS visibility

    const int base = lane * PPT;
    f32x2 px[NPAIR], py[NPAIR], pz[NPAIR], dist2[NPAIR];
#pragma unroll
    for (int j = 0; j < NPAIR; ++j) {
        float4 a = pos4[base + 2 * j];
        float4 c = pos4[base + 2 * j + 1];
        px[j] = (f32x2){a.x, c.x};
        py[j] = (f32x2){a.y, c.y};
        pz[j] = (f32x2){a.z, c.z};
        dist2[j] = (f32x2){__builtin_inff(), __builtin_inff()};
    }

    if (lane == 0) idx_out[b * MM] = 0;    // idx[0]=0 (scan records before update)
    float4 lp = pos4[0];
    float lx = lp.x, ly = lp.y, lz = lp.z;

    for (int m = 1; m < MM; ++m) {
        // ---- dist update: packed pairs, separate roundings, no FMA (bit-exact)
        {
#pragma clang fp contract(off)
            f32x2 vx = {lx, lx}, vy = {ly, ly}, vz = {lz, lz};
#pragma unroll
            for (int j = 0; j < NPAIR; ++j) {
                f32x2 dx = px[j] - vx;
                f32x2 dy = py[j] - vy;
                f32x2 dz = pz[j] - vz;
                f32x2 d  = dx * dx + dy * dy;
                d = d + dz * dz;
                dist2[j] = __builtin_elementwise_min(dist2[j], d);
            }
        }

        // ---- lane max of 64: 4 independent accumulator chains (ILP), then fold
        float ta = fmaxf(dist2[0].x, dist2[0].y);
        float tb = fmaxf(dist2[1].x, dist2[1].y);
        float tc = fmaxf(dist2[2].x, dist2[2].y);
        float td = fmaxf(dist2[3].x, dist2[3].y);
#pragma unroll
        for (int j = 4; j < NPAIR; j += 4) {
            ta = fmaxf(ta, fmaxf(dist2[j].x,     dist2[j].y));
            tb = fmaxf(tb, fmaxf(dist2[j + 1].x, dist2[j + 1].y));
            tc = fmaxf(tc, fmaxf(dist2[j + 2].x, dist2[j + 2].y));
            td = fmaxf(td, fmaxf(dist2[j + 3].x, dist2[j + 3].y));
        }
        float tmax = fmaxf(fmaxf(ta, tb), fmaxf(tc, td));

        // ---- local scan vs tmax: lowest k with dist==tmax, 4 umin chains
        u32 sa = 64u, sb = 64u, sc = 64u, sd = 64u;   // sentinel 64 = inline const
#pragma unroll
        for (int j = 0; j < NPAIR; j += 4) {
            sa = umin3(sa, (dist2[j].x     == tmax) ? (u32)(2 * j)     : 64u,
                           (dist2[j].y     == tmax) ? (u32)(2 * j + 1) : 64u);
            sb = umin3(sb, (dist2[j + 1].x == tmax) ? (u32)(2 * j + 2) : 64u,
                           (dist2[j + 1].y == tmax) ? (u32)(2 * j + 3) : 64u);
            sc = umin3(sc, (dist2[j + 2].x == tmax) ? (u32)(2 * j + 4) : 64u,
                           (dist2[j + 2].y == tmax) ? (u32)(2 * j + 5) : 64u);
            sd = umin3(sd, (dist2[j + 3].x == tmax) ? (u32)(2 * j + 6) : 64u,
                           (dist2[j + 3].y == tmax) ? (u32)(2 * j + 7) : 64u);
        }
        u32 sl = umin3(umin2(sa, sb), sc, sd);
        u32 gidx = (u32)base + sl;

        float4 sp = pos4[gidx];        // speculative winner coords (hidden under reduces)

        float wmax = wave_fmax(tmax);
        u32 cand = (tmax == wmax) ? gidx : 0xFFFFFFFFu;
        u32 widx = wave_umin(cand);

        // ---- broadcast winner coords from owner lane (gidx>>6 == owning lane)
        int owner = (int)(__builtin_amdgcn_readfirstlane((int)widx) >> 6);
        lx = __int_as_float(__builtin_amdgcn_readlane(__float_as_int(sp.x), owner));
        ly = __int_as_float(__builtin_amdgcn_readlane(__float_as_int(sp.y), owner));
        lz = __int_as_float(__builtin_amdgcn_readlane(__float_as_int(sp.z), owner));

        if (lane == 0) idx_out[b * MM + m] = (int)widx;   // no barrier -> no drain
    }
}

// ---------------------------------------------------------------------------
// Phase 2a: gather sampled_x (float4-vectorized).
// ---------------------------------------------------------------------------
__global__ void gather_x_kernel(const float* __restrict__ x,
                                const int* __restrict__ idx,
                                float* __restrict__ out) {
    int t = blockIdx.x * blockDim.x + threadIdx.x;
    if (t >= BB * MM * DD / 4) return;
    int row = t >> 5;               // DD/4 = 32 float4 per row
    int c4  = (t & 31) << 2;
    int b   = row >> 10;
    int n   = idx[row];
    const float4 v = *(const float4*)(x + ((size_t)(b * NN + n) * DD + c4));
    *(float4*)(out + (size_t)row * DD + c4) = v;
}

// ---------------------------------------------------------------------------
// Phase 2b: gather sampled_pos + batch ids (as float).
// ---------------------------------------------------------------------------
__global__ void gather_pb_kernel(const float* __restrict__ pos,
                                 const int* __restrict__ idx,
                                 float* __restrict__ spos,
                                 float* __restrict__ sbatch) {
    int r = blockIdx.x * blockDim.x + threadIdx.x;
    if (r >= BB * MM) return;
    int b = r >> 10;
    int n = idx[r];
    const float* p = pos + (size_t)(b * NN + n) * 3;
    spos[r * 3 + 0] = p[0];
    spos[r * 3 + 1] = p[1];
    spos[r * 3 + 2] = p[2];
    sbatch[r] = (float)b;
}

// ---------------------------------------------------------------------------
// Phase 3: radius adjacency, bit-exact d2 (no FMA).
// ---------------------------------------------------------------------------
__global__ void adj_kernel(const float* __restrict__ spos,
                           float* __restrict__ adj) {
    int row = blockIdx.x;           // b*MM + i
    int b   = row >> 10;
    int i   = row & (MM - 1);
    const float* pb = spos + (size_t)b * MM * 3;
    float xi = pb[i * 3 + 0];
    float yi = pb[i * 3 + 1];
    float zi = pb[i * 3 + 2];

    int j0 = threadIdx.x << 2;
    float4 r;
    float* o = adj + (size_t)row * MM;
#pragma unroll
    for (int k = 0; k < 4; ++k) {
        int j = j0 + k;
        float dx = xi - pb[j * 3 + 0];
        float dy = yi - pb[j * 3 + 1];
        float dz = zi - pb[j * 3 + 2];
        float d2 = __fadd_rn(__fadd_rn(__fmul_rn(dx, dx), __fmul_rn(dy, dy)),
                             __fmul_rn(dz, dz));
        float v = (d2 <= RADIUS2 && j != i) ? 1.0f : 0.0f;
        ((float*)&r)[k] = v;
    }
    *(float4*)(o + j0) = r;
}

// ---------------------------------------------------------------------------
extern "C" void kernel_launch(void* const* d_in, const int* in_sizes, int n_in,
                              void* d_out, int out_size, void* d_ws, size_t ws_size,
                              hipStream_t stream) {
    const float* x   = (const float*)d_in[0];
    const float* pos = (const float*)d_in[1];

    float* out    = (float*)d_out;
    int*   idx_ws = (int*)d_ws;                 // BB*MM ints = 64 KB scratch

    float* sx   = out;                          // [BB*MM, DD]
    float* spos = sx + (size_t)BB * MM * DD;    // [BB*MM, 3]
    float* sbat = spos + (size_t)BB * MM * 3;   // [BB*MM]
    float* adj  = sbat + (size_t)BB * MM;       // [BB, MM, MM]

    fps_kernel<<<BB, TPB, 0, stream>>>(pos, idx_ws);
    gather_x_kernel<<<(BB * MM * DD / 4 + 255) / 256, 256, 0, stream>>>(x, idx_ws, sx);
    gather_pb_kernel<<<(BB * MM + 255) / 256, 256, 0, stream>>>(pos, idx_ws, spos, sbat);
    adj_kernel<<<BB * MM, 256, 0, stream>>>(spos, adj);
}

// Round 7
// 1010.691 us; speedup vs baseline: 1.5728x; 1.5728x over previous
//
#include <hip/hip_runtime.h>
#include <stdint.h>

#define BB 16
#define NN 4096
#define DD 128
#define MM 1024
#define RADIUS2 0.04f
#define TPB 512            // 8 waves: 2 graphs x 4 waves -> 2 indep chains per SIMD
#define PPT 16             // points per lane (register-resident, proven r5)
#define NPAIR (PPT / 2)

typedef unsigned long long u64;
typedef unsigned int u32;
typedef float f32x2 __attribute__((ext_vector_type(2)));
typedef unsigned int uint2v __attribute__((ext_vector_type(2)));

__device__ __forceinline__ u32 umin2(u32 a, u32 b) { return a < b ? a : b; }
__device__ __forceinline__ u32 umin3(u32 a, u32 b, u32 c) { return umin2(umin2(a, b), c); }
__device__ __forceinline__ float fmax3(float a, float b, float c) { return fmaxf(fmaxf(a, b), c); }

template <int CTRL>
__device__ __forceinline__ float dpp_fmax(float v) {
    int o = __builtin_amdgcn_update_dpp(0, __float_as_int(v), CTRL, 0xF, 0xF, true);
    return fmaxf(v, __int_as_float(o));
}
__device__ __forceinline__ float xor16_fmax(float v) {
#if __has_builtin(__builtin_amdgcn_permlane16_swap)
    uint2v r = __builtin_amdgcn_permlane16_swap(__float_as_uint(v), __float_as_uint(v), false, false);
    return fmaxf(__uint_as_float(r[0]), __uint_as_float(r[1]));
#else
    int o = __builtin_amdgcn_ds_swizzle(__float_as_int(v), 0x401F);
    return fmaxf(v, __int_as_float(o));
#endif
}
__device__ __forceinline__ float xor32_fmax(float v) {
#if __has_builtin(__builtin_amdgcn_permlane32_swap)
    uint2v r = __builtin_amdgcn_permlane32_swap(__float_as_uint(v), __float_as_uint(v), false, false);
    return fmaxf(__uint_as_float(r[0]), __uint_as_float(r[1]));
#else
    return fmaxf(v, __shfl_xor(v, 32, 64));
#endif
}
__device__ __forceinline__ float wave_fmax(float v) {
    v = dpp_fmax<0xB1>(v);     // quad_perm xor1
    v = dpp_fmax<0x4E>(v);     // quad_perm xor2
    v = dpp_fmax<0x141>(v);    // row_half_mirror
    v = dpp_fmax<0x140>(v);    // row_mirror
    v = xor16_fmax(v);
    v = xor32_fmax(v);
    return v;
}

// ---------------------------------------------------------------------------
// FPS: 8 blocks, each runs TWO graphs (waves 0-3 -> graph 2b, waves 4-7 ->
// graph 2b+1). Each SIMD hosts one wave of each graph: graph A's barrier/LDS
// stalls are filled by graph B's VALU issue. Intra-wave argmax index via
// ballot+ctz (lowest candidate lane = lowest global index, contiguous
// ownership) -- removes the 6-level wave_umin from the serial chain.
// ---------------------------------------------------------------------------
__global__ __launch_bounds__(TPB) void fps_kernel(const float* __restrict__ pos,
                                                  int* __restrict__ idx_out) {
    const int blk  = blockIdx.x;           // 0..7
    const int tid  = threadIdx.x;          // 0..511
    const int half = tid >> 8;             // 0/1 -> which graph
    const int ht   = tid & 255;            // thread id within half
    const int wid  = ht >> 6;              // wave within half (0..3)
    const int lane = tid & 63;
    const int g    = blk * 2 + half;       // global graph id

    __shared__ float4 pos4[2 * NN];        // 128 KB (two graphs, xyz_ padded)
    __shared__ float4 fpart[2][2][4];      // [half][buf][wave] {wmax,x,y,z}
    __shared__ u32    ipart[2][2][4];
    __shared__ int    trace[2][MM];        // 8 KB

    const float* pg = pos + (size_t)g * NN * 3;
    float* pbase = (float*)&pos4[half * NN];
    for (int k = ht; k < NN * 3; k += 256)
        pbase[(k / 3) * 4 + (k % 3)] = pg[k];
    if (ht == 0) trace[half][0] = 0;       // idx[0]=0 (scan records before update)
    __syncthreads();

    const int base = ht * PPT;             // contiguous ownership within half
    const float4* mypos = &pos4[half * NN];
    f32x2 px[NPAIR], py[NPAIR], pz[NPAIR], dist2[NPAIR];
#pragma unroll
    for (int j = 0; j < NPAIR; ++j) {
        float4 a = mypos[base + 2 * j];
        float4 c = mypos[base + 2 * j + 1];
        px[j] = (f32x2){a.x, c.x};
        py[j] = (f32x2){a.y, c.y};
        pz[j] = (f32x2){a.z, c.z};
        dist2[j] = (f32x2){__builtin_inff(), __builtin_inff()};
    }

    float4 lp = mypos[0];
    float lx = lp.x, ly = lp.y, lz = lp.z;

    for (int m = 1; m < MM; ++m) {
        // ---- dist update: packed pairs, separate roundings, no FMA (bit-exact)
        {
#pragma clang fp contract(off)
            f32x2 vx = {lx, lx}, vy = {ly, ly}, vz = {lz, lz};
#pragma unroll
            for (int j = 0; j < NPAIR; ++j) {
                f32x2 dx = px[j] - vx;
                f32x2 dy = py[j] - vy;
                f32x2 dz = pz[j] - vz;
                f32x2 d  = dx * dx + dy * dy;
                d = d + dz * dz;
                dist2[j] = __builtin_elementwise_min(dist2[j], d);
            }
        }

        // ---- lane max of 16 (max3 tree)
        float t0 = fmaxf(dist2[0].x, dist2[0].y);
        float t1 = fmaxf(dist2[1].x, dist2[1].y);
        float t2 = fmaxf(dist2[2].x, dist2[2].y);
        float t3 = fmaxf(dist2[3].x, dist2[3].y);
        float t4 = fmaxf(dist2[4].x, dist2[4].y);
        float t5 = fmaxf(dist2[5].x, dist2[5].y);
        float t6 = fmaxf(dist2[6].x, dist2[6].y);
        float t7 = fmaxf(dist2[7].x, dist2[7].y);
        float tmax = fmax3(fmax3(t0, t1, t2), fmax3(t3, t4, t5), fmaxf(t6, t7));

        // ---- local scan vs tmax (lowest k), off the critical path
        u32 c[PPT];
#pragma unroll
        for (int j = 0; j < NPAIR; ++j) {
            c[2 * j]     = (dist2[j].x == tmax) ? (u32)(2 * j)     : 64u;
            c[2 * j + 1] = (dist2[j].y == tmax) ? (u32)(2 * j + 1) : 64u;
        }
        u32 a0 = umin3(c[0],  c[1],  c[2]);
        u32 a1 = umin3(c[3],  c[4],  c[5]);
        u32 a2 = umin3(c[6],  c[7],  c[8]);
        u32 a3 = umin3(c[9],  c[10], c[11]);
        u32 a4 = umin3(c[12], c[13], c[14]);
        u32 sl = umin3(umin3(a0, a1, a2), umin2(a3, a4), c[15]);
        u32 gidx = (u32)base + sl;

        float4 sp = mypos[gidx];           // speculative winner coords (overlapped)

        float wmax = wave_fmax(tmax);

        // ---- intra-wave winner: lowest candidate lane = lowest global index
        u64 mk   = __ballot(tmax == wmax);
        int owner = (int)__builtin_ctzll(mk);    // s_ff1_i32_b64 (uniform)

        const int buf = m & 1;
        if (lane == owner) {               // owner holds gidx and sp in registers
            fpart[half][buf][wid] = make_float4(wmax, sp.x, sp.y, sp.z);
            ipart[half][buf][wid] = gidx;
        }
        __syncthreads();

        float4 q0 = fpart[half][buf][0];
        float4 q1 = fpart[half][buf][1];
        float4 q2 = fpart[half][buf][2];
        float4 q3 = fpart[half][buf][3];
        float gmx = fmaxf(fmaxf(q0.x, q1.x), fmaxf(q2.x, q3.x));
        // descending selects: wave 0 wins ties (lowest index range)
        float nx = q3.y, ny = q3.z, nz = q3.w;
        bool b2 = (q2.x == gmx); nx = b2 ? q2.y : nx; ny = b2 ? q2.z : ny; nz = b2 ? q2.w : nz;
        bool b1 = (q1.x == gmx); nx = b1 ? q1.y : nx; ny = b1 ? q1.z : ny; nz = b1 ? q1.w : nz;
        bool b0 = (q0.x == gmx); nx = b0 ? q0.y : nx; ny = b0 ? q0.z : ny; nz = b0 ? q0.w : nz;
        lx = nx; ly = ny; lz = nz;

        if (ht == 0) {                     // LDS trace (no vmcnt in loop)
            u32 li = ipart[half][buf][3];
            li = b2 ? ipart[half][buf][2] : li;
            li = b1 ? ipart[half][buf][1] : li;
            li = b0 ? ipart[half][buf][0] : li;
            trace[half][m] = (int)li;
        }
    }

    __syncthreads();                       // make trace visible
    for (int k = ht; k < MM; k += 256)     // batched dump
        idx_out[g * MM + k] = trace[half][k];
}

// ---------------------------------------------------------------------------
// Phase 2a: gather sampled_x (float4-vectorized).
// ---------------------------------------------------------------------------
__global__ void gather_x_kernel(const float* __restrict__ x,
                                const int* __restrict__ idx,
                                float* __restrict__ out) {
    int t = blockIdx.x * blockDim.x + threadIdx.x;
    if (t >= BB * MM * DD / 4) return;
    int row = t >> 5;               // DD/4 = 32 float4 per row
    int c4  = (t & 31) << 2;
    int b   = row >> 10;
    int n   = idx[row];
    const float4 v = *(const float4*)(x + ((size_t)(b * NN + n) * DD + c4));
    *(float4*)(out + (size_t)row * DD + c4) = v;
}

// ---------------------------------------------------------------------------
// Phase 2b: gather sampled_pos + batch ids (as float).
// ---------------------------------------------------------------------------
__global__ void gather_pb_kernel(const float* __restrict__ pos,
                                 const int* __restrict__ idx,
                                 float* __restrict__ spos,
                                 float* __restrict__ sbatch) {
    int r = blockIdx.x * blockDim.x + threadIdx.x;
    if (r >= BB * MM) return;
    int b = r >> 10;
    int n = idx[r];
    const float* p = pos + (size_t)(b * NN + n) * 3;
    spos[r * 3 + 0] = p[0];
    spos[r * 3 + 1] = p[1];
    spos[r * 3 + 2] = p[2];
    sbatch[r] = (float)b;
}

// ---------------------------------------------------------------------------
// Phase 3: radius adjacency, bit-exact d2 (no FMA).
// ---------------------------------------------------------------------------
__global__ void adj_kernel(const float* __restrict__ spos,
                           float* __restrict__ adj) {
    int row = blockIdx.x;           // b*MM + i
    int b   = row >> 10;
    int i   = row & (MM - 1);
    const float* pb = spos + (size_t)b * MM * 3;
    float xi = pb[i * 3 + 0];
    float yi = pb[i * 3 + 1];
    float zi = pb[i * 3 + 2];

    int j0 = threadIdx.x << 2;
    float4 r;
    float* o = adj + (size_t)row * MM;
#pragma unroll
    for (int k = 0; k < 4; ++k) {
        int j = j0 + k;
        float dx = xi - pb[j * 3 + 0];
        float dy = yi - pb[j * 3 + 1];
        float dz = zi - pb[j * 3 + 2];
        float d2 = __fadd_rn(__fadd_rn(__fmul_rn(dx, dx), __fmul_rn(dy, dy)),
                             __fmul_rn(dz, dz));
        float v = (d2 <= RADIUS2 && j != i) ? 1.0f : 0.0f;
        ((float*)&r)[k] = v;
    }
    *(float4*)(o + j0) = r;
}

// ---------------------------------------------------------------------------
extern "C" void kernel_launch(void* const* d_in, const int* in_sizes, int n_in,
                              void* d_out, int out_size, void* d_ws, size_t ws_size,
                              hipStream_t stream) {
    const float* x   = (const float*)d_in[0];
    const float* pos = (const float*)d_in[1];

    float* out    = (float*)d_out;
    int*   idx_ws = (int*)d_ws;                 // BB*MM ints = 64 KB scratch

    float* sx   = out;                          // [BB*MM, DD]
    float* spos = sx + (size_t)BB * MM * DD;    // [BB*MM, 3]
    float* sbat = spos + (size_t)BB * MM * 3;   // [BB*MM]
    float* adj  = sbat + (size_t)BB * MM;       // [BB, MM, MM]

    fps_kernel<<<BB / 2, TPB, 0, stream>>>(pos, idx_ws);
    gather_x_kernel<<<(BB * MM * DD / 4 + 255) / 256, 256, 0, stream>>>(x, idx_ws, sx);
    gather_pb_kernel<<<(BB * MM + 255) / 256, 256, 0, stream>>>(pos, idx_ws, spos, sbat);
    adj_kernel<<<BB * MM, 256, 0, stream>>>(spos, adj);
}

// Round 8
// 744.016 us; speedup vs baseline: 2.1365x; 1.3584x over previous
//
#include <hip/hip_runtime.h>
#include <stdint.h>

#define BB 16
#define NN 4096
#define DD 128
#define MM 1024
#define RADIUS2 0.04f
#define TPB 256
#define PPT 16             // points per lane (register-resident, proven r3/r5)
#define NPAIR (PPT / 2)
#define NW 4               // 4 waves, 1 per SIMD

typedef unsigned long long u64;
typedef unsigned int u32;
typedef float f32x2 __attribute__((ext_vector_type(2)));
typedef unsigned int uint2v __attribute__((ext_vector_type(2)));

__device__ __forceinline__ u32 umin2(u32 a, u32 b) { return a < b ? a : b; }
__device__ __forceinline__ u32 umin3(u32 a, u32 b, u32 c) { return umin2(umin2(a, b), c); }
__device__ __forceinline__ float fmax3(float a, float b, float c) { return fmaxf(fmaxf(a, b), c); }

template <int CTRL>
__device__ __forceinline__ float dpp_fmax(float v) {
    int o = __builtin_amdgcn_update_dpp(0, __float_as_int(v), CTRL, 0xF, 0xF, true);
    return fmaxf(v, __int_as_float(o));
}
__device__ __forceinline__ float xor16_fmax(float v) {
#if __has_builtin(__builtin_amdgcn_permlane16_swap)
    uint2v r = __builtin_amdgcn_permlane16_swap(__float_as_uint(v), __float_as_uint(v), false, false);
    return fmaxf(__uint_as_float(r[0]), __uint_as_float(r[1]));
#else
    int o = __builtin_amdgcn_ds_swizzle(__float_as_int(v), 0x401F);
    return fmaxf(v, __int_as_float(o));
#endif
}
__device__ __forceinline__ float xor32_fmax(float v) {
#if __has_builtin(__builtin_amdgcn_permlane32_swap)
    uint2v r = __builtin_amdgcn_permlane32_swap(__float_as_uint(v), __float_as_uint(v), false, false);
    return fmaxf(__uint_as_float(r[0]), __uint_as_float(r[1]));
#else
    return fmaxf(v, __shfl_xor(v, 32, 64));
#endif
}
__device__ __forceinline__ float wave_fmax(float v) {
    v = dpp_fmax<0xB1>(v);     // quad_perm xor1
    v = dpp_fmax<0x4E>(v);     // quad_perm xor2
    v = dpp_fmax<0x141>(v);    // row_half_mirror
    v = dpp_fmax<0x140>(v);    // row_mirror
    v = xor16_fmax(v);
    v = xor32_fmax(v);
    return v;
}

// ---------------------------------------------------------------------------
// FPS: one block (4 waves) per graph, NO s_barrier in the loop. Cross-wave
// exchange via a 2-deep double-buffered LDS mailbox:
//   owner lane: ds_write_b128 {x,y,z,wmax} -> (fence) -> ds_write_b32 tag
//   every wave: speculatively read tags(b128)+4 data(b128) together, validate
//   all 4 tags == (m<<12)|*, retry if stale (rare; waves are symmetric).
// DS ops from one wave complete in order, so tag==m implies data is valid.
// 2-deep safety: overwriting buf (m&1) at iter m+2 requires all tags m+1,
// each published only after that wave folded iter m.
// Tie-break = lowest global index everywhere (lane scan umin; ballot+ctz
// lowest candidate lane; descending cross-wave fold, wave 0 priority).
// ---------------------------------------------------------------------------
__global__ __launch_bounds__(TPB) void fps_kernel(const float* __restrict__ pos,
                                                  int* __restrict__ idx_out) {
    const int b    = blockIdx.x;
    const int tid  = threadIdx.x;
    const int wid  = tid >> 6;
    const int lane = tid & 63;

    __shared__ float4 pos4[NN];                    // 64 KB, xyz_ padded
    __shared__ __align__(16) float4 cslot[2][NW];  // {x,y,z,wmax} per wave
    __shared__ __align__(16) u32    tslot[2][NW];  // (m<<12)|idx
    __shared__ int trace[MM];                      // 4 KB

    const float* pg = pos + (size_t)b * NN * 3;
    for (int k = tid; k < NN * 3; k += TPB)
        ((float*)&pos4[k / 3])[k % 3] = pg[k];
    if (tid < 8) ((u32*)tslot)[tid] = 0;           // tags start invalid (m>=1)
    if (tid == 0) trace[0] = 0;                    // idx[0]=0 (record-before-update)
    __syncthreads();                               // staging only

    const int base = tid * PPT;
    f32x2 px[NPAIR], py[NPAIR], pz[NPAIR], dist2[NPAIR];
#pragma unroll
    for (int j = 0; j < NPAIR; ++j) {
        float4 a = pos4[base + 2 * j];
        float4 c = pos4[base + 2 * j + 1];
        px[j] = (f32x2){a.x, c.x};
        py[j] = (f32x2){a.y, c.y};
        pz[j] = (f32x2){a.z, c.z};
        dist2[j] = (f32x2){__builtin_inff(), __builtin_inff()};
    }

    float4 lp = pos4[0];
    float lx = lp.x, ly = lp.y, lz = lp.z;

    for (int m = 1; m < MM; ++m) {
        // ---- dist update: packed pairs, separate roundings, no FMA (bit-exact)
        {
#pragma clang fp contract(off)
            f32x2 vx = {lx, lx}, vy = {ly, ly}, vz = {lz, lz};
#pragma unroll
            for (int j = 0; j < NPAIR; ++j) {
                f32x2 dx = px[j] - vx;
                f32x2 dy = py[j] - vy;
                f32x2 dz = pz[j] - vz;
                f32x2 d  = dx * dx + dy * dy;
                d = d + dz * dz;
                dist2[j] = __builtin_elementwise_min(dist2[j], d);
            }
        }

        // ---- lane max of 16 (max3 tree)
        float t0 = fmaxf(dist2[0].x, dist2[0].y);
        float t1 = fmaxf(dist2[1].x, dist2[1].y);
        float t2 = fmaxf(dist2[2].x, dist2[2].y);
        float t3 = fmaxf(dist2[3].x, dist2[3].y);
        float t4 = fmaxf(dist2[4].x, dist2[4].y);
        float t5 = fmaxf(dist2[5].x, dist2[5].y);
        float t6 = fmaxf(dist2[6].x, dist2[6].y);
        float t7 = fmaxf(dist2[7].x, dist2[7].y);
        float tmax = fmax3(fmax3(t0, t1, t2), fmax3(t3, t4, t5), fmaxf(t6, t7));

        // ---- local scan vs tmax (lowest k) -- fills DPP-chain bubbles
        u32 c[PPT];
#pragma unroll
        for (int j = 0; j < NPAIR; ++j) {
            c[2 * j]     = (dist2[j].x == tmax) ? (u32)(2 * j)     : 64u;
            c[2 * j + 1] = (dist2[j].y == tmax) ? (u32)(2 * j + 1) : 64u;
        }
        u32 a0 = umin3(c[0],  c[1],  c[2]);
        u32 a1 = umin3(c[3],  c[4],  c[5]);
        u32 a2 = umin3(c[6],  c[7],  c[8]);
        u32 a3 = umin3(c[9],  c[10], c[11]);
        u32 a4 = umin3(c[12], c[13], c[14]);
        u32 sl = umin3(umin3(a0, a1, a2), umin2(a3, a4), c[15]);
        u32 gidx = (u32)base + sl;

        float4 sp = pos4[gidx];            // speculative winner coords (overlapped)

        float wmax = wave_fmax(tmax);

        // ---- intra-wave winner: lowest candidate lane = lowest global index
        u64 mk    = __ballot(tmax == wmax);
        int owner = (int)__builtin_ctzll(mk);

        const int buf = m & 1;
        const u32 tagm = (u32)m << 12;
        if (lane == owner) {               // publish: data first, then tag
            cslot[buf][wid] = make_float4(sp.x, sp.y, sp.z, wmax);
            asm volatile("" ::: "memory"); // keep store order; DS is in-order per wave
            tslot[buf][wid] = tagm | gidx;
        }

        // ---- mailbox: issue tag + all data reads together, validate, retry
        uint4 tg; float4 q0, q1, q2, q3;
        do {
            asm volatile("" ::: "memory");
            tg = *(const uint4*)&tslot[buf][0];    // 1x ds_read_b128
            q0 = cslot[buf][0];
            q1 = cslot[buf][1];
            q2 = cslot[buf][2];
            q3 = cslot[buf][3];
        } while ((((tg.x ^ tagm) | (tg.y ^ tagm) | (tg.z ^ tagm) | (tg.w ^ tagm))
                  & 0xFFFFF000u) != 0);

        float g = fmaxf(fmaxf(q0.w, q1.w), fmaxf(q2.w, q3.w));
        // descending selects: wave 0 wins ties (lowest index range)
        float nx = q3.x, ny = q3.y, nz = q3.z; u32 li = tg.w & 0xFFFu;
        bool s2 = (q2.w == g); nx = s2 ? q2.x : nx; ny = s2 ? q2.y : ny; nz = s2 ? q2.z : nz; li = s2 ? (tg.z & 0xFFFu) : li;
        bool s1 = (q1.w == g); nx = s1 ? q1.x : nx; ny = s1 ? q1.y : ny; nz = s1 ? q1.z : nz; li = s1 ? (tg.y & 0xFFFu) : li;
        bool s0 = (q0.w == g); nx = s0 ? q0.x : nx; ny = s0 ? q0.y : ny; nz = s0 ? q0.z : nz; li = s0 ? (tg.x & 0xFFFu) : li;
        lx = nx; ly = ny; lz = nz;

        if (tid == 0) trace[m] = (int)li;  // LDS only; dumped post-loop
    }

    __syncthreads();                       // trace visibility for the dump
    for (int k = tid; k < MM; k += TPB)
        idx_out[b * MM + k] = trace[k];
}

// ---------------------------------------------------------------------------
// Phase 2a: gather sampled_x (float4-vectorized).
// ---------------------------------------------------------------------------
__global__ void gather_x_kernel(const float* __restrict__ x,
                                const int* __restrict__ idx,
                                float* __restrict__ out) {
    int t = blockIdx.x * blockDim.x + threadIdx.x;
    if (t >= BB * MM * DD / 4) return;
    int row = t >> 5;               // DD/4 = 32 float4 per row
    int c4  = (t & 31) << 2;
    int b   = row >> 10;
    int n   = idx[row];
    const float4 v = *(const float4*)(x + ((size_t)(b * NN + n) * DD + c4));
    *(float4*)(out + (size_t)row * DD + c4) = v;
}

// ---------------------------------------------------------------------------
// Phase 2b: gather sampled_pos + batch ids (as float).
// ---------------------------------------------------------------------------
__global__ void gather_pb_kernel(const float* __restrict__ pos,
                                 const int* __restrict__ idx,
                                 float* __restrict__ spos,
                                 float* __restrict__ sbatch) {
    int r = blockIdx.x * blockDim.x + threadIdx.x;
    if (r >= BB * MM) return;
    int b = r >> 10;
    int n = idx[r];
    const float* p = pos + (size_t)(b * NN + n) * 3;
    spos[r * 3 + 0] = p[0];
    spos[r * 3 + 1] = p[1];
    spos[r * 3 + 2] = p[2];
    sbatch[r] = (float)b;
}

// ---------------------------------------------------------------------------
// Phase 3: radius adjacency, bit-exact d2 (no FMA).
// ---------------------------------------------------------------------------
__global__ void adj_kernel(const float* __restrict__ spos,
                           float* __restrict__ adj) {
    int row = blockIdx.x;           // b*MM + i
    int b   = row >> 10;
    int i   = row & (MM - 1);
    const float* pb = spos + (size_t)b * MM * 3;
    float xi = pb[i * 3 + 0];
    float yi = pb[i * 3 + 1];
    float zi = pb[i * 3 + 2];

    int j0 = threadIdx.x << 2;
    float4 r;
    float* o = adj + (size_t)row * MM;
#pragma unroll
    for (int k = 0; k < 4; ++k) {
        int j = j0 + k;
        float dx = xi - pb[j * 3 + 0];
        float dy = yi - pb[j * 3 + 1];
        float dz = zi - pb[j * 3 + 2];
        float d2 = __fadd_rn(__fadd_rn(__fmul_rn(dx, dx), __fmul_rn(dy, dy)),
                             __fmul_rn(dz, dz));
        float v = (d2 <= RADIUS2 && j != i) ? 1.0f : 0.0f;
        ((float*)&r)[k] = v;
    }
    *(float4*)(o + j0) = r;
}

// ---------------------------------------------------------------------------
extern "C" void kernel_launch(void* const* d_in, const int* in_sizes, int n_in,
                              void* d_out, int out_size, void* d_ws, size_t ws_size,
                              hipStream_t stream) {
    const float* x   = (const float*)d_in[0];
    const float* pos = (const float*)d_in[1];

    float* out    = (float*)d_out;
    int*   idx_ws = (int*)d_ws;                 // BB*MM ints = 64 KB scratch

    float* sx   = out;                          // [BB*MM, DD]
    float* spos = sx + (size_t)BB * MM * DD;    // [BB*MM, 3]
    float* sbat = spos + (size_t)BB * MM * 3;   // [BB*MM]
    float* adj  = sbat + (size_t)BB * MM;       // [BB, MM, MM]

    fps_kernel<<<BB, TPB, 0, stream>>>(pos, idx_ws);
    gather_x_kernel<<<(BB * MM * DD / 4 + 255) / 256, 256, 0, stream>>>(x, idx_ws, sx);
    gather_pb_kernel<<<(BB * MM + 255) / 256, 256, 0, stream>>>(pos, idx_ws, spos, sbat);
    adj_kernel<<<BB * MM, 256, 0, stream>>>(spos, adj);
}